// Round 12
// baseline (114.519 us; speedup 1.0000x reference)
//
#include <hip/hip_runtime.h>
#include <hip/hip_bf16.h>

// CrossViewAttention: B=4, V=6, C=256, H=W=64 (HW=4096), heads=8, dh=32.
//
// Pipeline (3 launches):
//   1. convert_weights: Wq/Wk/Wv/Wo fp32 -> bf16
//   2. transpose_mean:  x[b][v][c][w] -> xt[b][v][w][c] bf16, xbar[b][w][c] bf16
//   3. mega_kernel: per 32-pixel tile: Q GEMM -> per view {K GEMM, scores,
//      V GEMM, online-softmax PV} -> Wo GEMM -> d_out.
//
// Round-12 restructure: rounds 10/11 proved the allocator caps this kernel at
// 128 VGPRs (spilling the ~200-reg working set to scratch: WRITE_SIZE 31MB vs
// 17MB output). Fix by SHRINKING the working set to fit 128: 32-pixel blocks
// (acc 16 regs), weights streamed via 4-slot ring (32 regs, 3-kt lead),
// softmax split 2 threads/(px,h) pair (o[16], shfl_xor combine). LDS 68KB ->
// 2 blocks/CU (4 waves/SIMD): TLP hides stage drains and weight-load latency.

typedef __bf16 bf16x8 __attribute__((ext_vector_type(8)));
typedef float f32x4 __attribute__((ext_vector_type(4)));

#define HW 4096
#define C_DIM 256
#define NV 6
#define NB 4

__global__ __launch_bounds__(256) void convert_weights_kernel(
    const float* __restrict__ Wq, const float* __restrict__ Wk,
    const float* __restrict__ Wv, const float* __restrict__ Wo,
    __hip_bfloat16* __restrict__ out)
{
    const float* srcs[4] = {Wq, Wk, Wv, Wo};
    const int m = blockIdx.y;
    const int i = blockIdx.x * 256 + threadIdx.x;
    out[m * 65536 + i] = __float2bfloat16(srcs[m][i]);
}

// 64x64 tile transpose via LDS; accumulates per-view sum for xbar.
__global__ __launch_bounds__(256) void transpose_mean_kernel(
    const float* __restrict__ x,        // [B][V][C][HW]
    __hip_bfloat16* __restrict__ xt,    // [B][V][HW][C]
    __hip_bfloat16* __restrict__ xbar)  // [B][HW][C]
{
    __shared__ float tile[64][65];
    const int w0 = blockIdx.x * 64;
    const int c0 = blockIdx.y * 64;
    const int b  = blockIdx.z;
    const int t  = threadIdx.x;
    const int li = t & 63;
    const int qi = t >> 6;
    float acc[16];
#pragma unroll
    for (int i = 0; i < 16; ++i) acc[i] = 0.f;

    for (int v = 0; v < NV; ++v) {
        const float* src = x + (((size_t)b * NV + v) * C_DIM + c0) * HW + w0;
#pragma unroll
        for (int i = 0; i < 16; ++i) {
            const int c = qi + 4 * i;
            tile[li][c] = src[(size_t)c * HW + li];
        }
        __syncthreads();
        __hip_bfloat16* dst = xt + (((size_t)b * NV + v) * HW + w0) * C_DIM + c0;
#pragma unroll
        for (int i = 0; i < 16; ++i) {
            const int w = qi + 4 * i;
            const float val = tile[w][li];
            acc[i] += val;
            dst[(size_t)w * C_DIM + li] = __float2bfloat16(val);
        }
        __syncthreads();
    }
    __hip_bfloat16* dbar = xbar + ((size_t)b * HW + w0) * C_DIM + c0;
#pragma unroll
    for (int i = 0; i < 16; ++i) {
        const int w = qi + 4 * i;
        dbar[(size_t)w * C_DIM + li] = __float2bfloat16(acc[i] * (1.f / 6.f));
    }
}

// Mega kernel: 512 threads (8 waves), block owns 32 pixels of batch b.
// Per-wave GEMM: M=32 (i<2), N=32 (j<2, wave wv owns cols wv*32..+31), K=256.
// LDS: Abuf 2x16KB ([kb 0..31][row 0..31][8] bf16) + T2[256][36] f32
// (col-major C tile [channel][pixel]; pad 36 keeps f32x4 rows 16B-aligned).
// Weights streamed from L2 per phase via 4-slot ring, 3-kt prefetch lead.
__global__ __launch_bounds__(512) void mega_kernel(
    const __hip_bfloat16* __restrict__ xt,    // [B*V][4096][256]
    const __hip_bfloat16* __restrict__ xbar,  // [B][4096][256]
    const __hip_bfloat16* __restrict__ Wq,
    const __hip_bfloat16* __restrict__ Wk,
    const __hip_bfloat16* __restrict__ Wv,
    const __hip_bfloat16* __restrict__ Wo,
    float* __restrict__ out)                  // [B][256][4096]
{
    __shared__ __align__(16) __hip_bfloat16 Abuf[2][8192];   // 2 x 16 KB
    __shared__ __align__(16) float T2[256][36];              // 36 KB
    const size_t SL = (size_t)HW * C_DIM;
    const int w0 = blockIdx.x * 32;
    const int b  = blockIdx.y;
    const int t  = threadIdx.x, wv = t >> 6, l = t & 63;
    const int kb_l = l >> 4, rl = l & 15, lq = l >> 4;
    // softmax mapping: 2 threads per (pixel, head) pair, 16 channels each
    const int pr = t >> 1;
    const int px = pr & 31, h = pr >> 5, sub = t & 1;
    const int c0 = h * 32 + sub * 16;

    f32x4 acc[2][2];
    auto zacc = [&]() {
#pragma unroll
        for (int i = 0; i < 2; ++i)
#pragma unroll
            for (int j = 0; j < 2; ++j) {
                acc[i][j][0] = 0.f; acc[i][j][1] = 0.f;
                acc[i][j][2] = 0.f; acc[i][j][3] = 0.f;
            }
    };

    // stage 32x256 bf16 tile (16KB, 16 chunks of 1KB, 2 per wave).
    // linear LDS dest == [kb][row][8] layout given per-lane src below.
    auto stageA = [&](int buf, const __hip_bfloat16* src) {
#pragma unroll
        for (int c2 = 0; c2 < 2; ++c2) {
            const int ch = wv * 2 + c2;               // chunk 0..15
            const int kb = ch * 2 + (l >> 5);         // kb 0..31
            const __hip_bfloat16* g = src + (size_t)(w0 + (l & 31)) * 256 + kb * 8;
            __builtin_amdgcn_global_load_lds(
                (const __attribute__((address_space(1))) void*)g,
                (__attribute__((address_space(3))) void*)(&Abuf[buf][ch * 512]),
                16, 0, 0);
        }
    };

    // one GEMM phase: A from LDS, B (weights) streamed via 4-slot ring
    auto gemmStream = [&](int buf, const __hip_bfloat16* W) {
        const __hip_bfloat16* wb = W + (size_t)(wv * 32 + rl) * 256 + kb_l * 8;
        bf16x8 bq[4][2];                              // ring; indices unroll-constant
#pragma unroll
        for (int p = 0; p < 3; ++p)
#pragma unroll
            for (int j = 0; j < 2; ++j)
                bq[p][j] = *(const bf16x8*)(wb + p * 32 + j * 4096);
#pragma unroll
        for (int kt = 0; kt < 8; ++kt) {
            if (kt + 3 < 8) {
#pragma unroll
                for (int j = 0; j < 2; ++j)
                    bq[(kt + 3) & 3][j] = *(const bf16x8*)(wb + (kt + 3) * 32 + j * 4096);
            }
            bf16x8 af[2];
#pragma unroll
            for (int i = 0; i < 2; ++i)
                af[i] = *(const bf16x8*)&Abuf[buf][(kt * 4 + kb_l) * 256 + (i * 16 + rl) * 8];
#pragma unroll
            for (int i = 0; i < 2; ++i)
#pragma unroll
                for (int j = 0; j < 2; ++j)
                    acc[i][j] = __builtin_amdgcn_mfma_f32_16x16x32_bf16(af[i], bq[kt & 3][j], acc[i][j], 0, 0, 0);
        }
    };

    // acc -> T2 col-major [channel][pixel]: 4x ds_write_b128
    auto writeT2 = [&]() {
#pragma unroll
        for (int i = 0; i < 2; ++i)
#pragma unroll
            for (int j = 0; j < 2; ++j)
                *(f32x4*)&T2[wv * 32 + j * 16 + rl][i * 16 + lq * 4] = acc[i][j];
    };

    // ---- Q phase ----
    stageA(0, xbar + (size_t)b * SL);
    __syncthreads();                          // S0: xbar tile ready
    zacc();
    gemmStream(0, Wq);
    stageA(1, xt + (size_t)(b * NV) * SL);    // view-0 tile (drains at S1)
    writeT2();
    __syncthreads();                          // S1: Q in T2; view-0 staged

    const float scale = 0.17677669529663687f; // 32^-0.5
    bf16x8 qbf[2];
#pragma unroll
    for (int i = 0; i < 2; ++i)
#pragma unroll
        for (int j = 0; j < 8; ++j)
            qbf[i][j] = (__bf16)(T2[c0 + i * 8 + j][px] * scale);

    float m = -1e30f, den = 0.f;
    float o[16];
#pragma unroll
    for (int cc = 0; cc < 16; ++cc) o[cc] = 0.f;

    // ---- view loop ----
    for (int v = 0; v < NV; ++v) {
        const int buf = (v + 1) & 1;          // v0->1, v1->0, ...
        __syncthreads();                      // S2: prior T2 reads done
        if (v < NV - 1) stageA(buf ^ 1, xt + (size_t)(b * NV + v + 1) * SL);
        zacc();
        gemmStream(buf, Wk);
        writeT2();
        __syncthreads();                      // S3: K in T2; next tile staged

        float s = 0.f;
#pragma unroll
        for (int i = 0; i < 2; ++i)
#pragma unroll
            for (int j = 0; j < 8; ++j)
                s += (float)qbf[i][j] * T2[c0 + i * 8 + j][px];
        s += __shfl_xor(s, 1);                // combine the pair's halves
        const float mn = fmaxf(m, s);
        const float f  = __expf(m - mn);
        const float e  = __expf(s - mn);
        den = den * f + e;
        m = mn;
#pragma unroll
        for (int cc = 0; cc < 16; ++cc) o[cc] *= f;
        __syncthreads();                      // S4: score reads done, T2 free

        zacc();
        gemmStream(buf, Wv);
        writeT2();
        __syncthreads();                      // S5: V in T2
#pragma unroll
        for (int cc = 0; cc < 16; ++cc) o[cc] += e * T2[c0 + cc][px];
    }

    // ---- epilogue: attn tile -> Abuf[0] (A layout), Wo GEMM, direct stores ----
    const float inv = 1.f / den;
#pragma unroll
    for (int k2 = 0; k2 < 2; ++k2) {
        bf16x8 ov;
#pragma unroll
        for (int k = 0; k < 8; ++k) ov[k] = (__bf16)(o[k2 * 8 + k] * inv);
        const int kb = (c0 >> 3) + k2;        // channel block 0..31
        *(bf16x8*)&Abuf[0][kb * 256 + px * 8] = ov;
    }
    __syncthreads();                          // S6: attn tile ready
    zacc();
    gemmStream(0, Wo);

    float* op = out + (size_t)b * C_DIM * HW;
#pragma unroll
    for (int i = 0; i < 2; ++i)
#pragma unroll
        for (int j = 0; j < 2; ++j) {
            const int col = wv * 32 + j * 16 + rl;
            *(f32x4*)(op + (size_t)col * HW + w0 + i * 16 + lq * 4) = acc[i][j];
        }
}

extern "C" void kernel_launch(void* const* d_in, const int* in_sizes, int n_in,
                              void* d_out, int out_size, void* d_ws, size_t ws_size,
                              hipStream_t stream)
{
    const float* x  = (const float*)d_in[0];
    const float* Wq = (const float*)d_in[1];
    const float* Wk = (const float*)d_in[2];
    const float* Wv = (const float*)d_in[3];
    const float* Wo = (const float*)d_in[4];
    (void)in_sizes; (void)n_in; (void)out_size; (void)ws_size;

    char* ws = (char*)d_ws;
    const size_t MB = 1024ull * 1024ull;
    const size_t SL = (size_t)HW * C_DIM;

    __hip_bfloat16* Wbf  = (__hip_bfloat16*)(ws);            // 512 KB
    __hip_bfloat16* xt   = (__hip_bfloat16*)(ws + 1 * MB);   // 48 MB [4*6][4096][256]
    __hip_bfloat16* xbar = (__hip_bfloat16*)(ws + 49 * MB);  // 8 MB  [4][4096][256]

    const __hip_bfloat16* WqB = Wbf;
    const __hip_bfloat16* WkB = Wbf + 65536;
    const __hip_bfloat16* WvB = Wbf + 131072;
    const __hip_bfloat16* WoB = Wbf + 196608;

    convert_weights_kernel<<<dim3(256, 4), 256, 0, stream>>>(Wq, Wk, Wv, Wo, Wbf);
    transpose_mean_kernel<<<dim3(HW / 64, C_DIM / 64, NB), 256, 0, stream>>>(x, xt, xbar);
    mega_kernel<<<dim3(HW / 32, NB), 512, 0, stream>>>(xt, xbar, WqB, WkB, WvB, WoB, (float*)d_out);
}

// Round 13
// 107.672 us; speedup vs baseline: 1.0636x; 1.0636x over previous
//
#include <hip/hip_runtime.h>
#include <hip/hip_bf16.h>

// CrossViewAttention: B=4, V=6, C=256, H=W=64 (HW=4096), heads=8, dh=32.
//
// Pipeline (3 launches):
//   1. convert_weights: Wq/Wk/Wv/Wo fp32 -> bf16
//   2. transpose_mean:  x[b][v][c][w] -> xt[b][v][w][c] bf16, xbar[b][w][c] bf16
//   3. mega_kernel (round-13 rewrite): 32-px blocks, 8 waves, wave == head.
//      Q GEMM -> per view ONE pass {K-MFMA + V-MFMA interleaved on same A-tile},
//      scores = per-lane Q*K product + 16-lane shfl butterfly (Q/K accs share
//      the MFMA C-layout), online softmax + PV scaling all in registers.
//      NO K/V LDS round-trip (the T2 tile of rounds 9-12 is gone), ONE barrier
//      per view. LDS = 2 x 16.6 KB A-tiles only.

typedef __bf16 bf16x8 __attribute__((ext_vector_type(8)));
typedef __bf16 bf16x4 __attribute__((ext_vector_type(4)));
typedef float f32x4 __attribute__((ext_vector_type(4)));

#define HW 4096
#define C_DIM 256
#define NV 6
#define NB 4

__global__ __launch_bounds__(256) void convert_weights_kernel(
    const float* __restrict__ Wq, const float* __restrict__ Wk,
    const float* __restrict__ Wv, const float* __restrict__ Wo,
    __hip_bfloat16* __restrict__ out)
{
    const float* srcs[4] = {Wq, Wk, Wv, Wo};
    const int m = blockIdx.y;
    const int i = blockIdx.x * 256 + threadIdx.x;
    out[m * 65536 + i] = __float2bfloat16(srcs[m][i]);
}

// 64x64 tile transpose via LDS; accumulates per-view sum for xbar.
__global__ __launch_bounds__(256) void transpose_mean_kernel(
    const float* __restrict__ x,        // [B][V][C][HW]
    __hip_bfloat16* __restrict__ xt,    // [B][V][HW][C]
    __hip_bfloat16* __restrict__ xbar)  // [B][HW][C]
{
    __shared__ float tile[64][65];
    const int w0 = blockIdx.x * 64;
    const int c0 = blockIdx.y * 64;
    const int b  = blockIdx.z;
    const int t  = threadIdx.x;
    const int li = t & 63;
    const int qi = t >> 6;
    float acc[16];
#pragma unroll
    for (int i = 0; i < 16; ++i) acc[i] = 0.f;

    for (int v = 0; v < NV; ++v) {
        const float* src = x + (((size_t)b * NV + v) * C_DIM + c0) * HW + w0;
#pragma unroll
        for (int i = 0; i < 16; ++i) {
            const int c = qi + 4 * i;
            tile[li][c] = src[(size_t)c * HW + li];
        }
        __syncthreads();
        __hip_bfloat16* dst = xt + (((size_t)b * NV + v) * HW + w0) * C_DIM + c0;
#pragma unroll
        for (int i = 0; i < 16; ++i) {
            const int w = qi + 4 * i;
            const float val = tile[w][li];
            acc[i] += val;
            dst[(size_t)w * C_DIM + li] = __float2bfloat16(val);
        }
        __syncthreads();
    }
    __hip_bfloat16* dbar = xbar + ((size_t)b * HW + w0) * C_DIM + c0;
#pragma unroll
    for (int i = 0; i < 16; ++i) {
        const int w = qi + 4 * i;
        dbar[(size_t)w * C_DIM + li] = __float2bfloat16(acc[i] * (1.f / 6.f));
    }
}

// Mega kernel v2: 512 threads (8 waves), block owns 32 pixels of batch b.
// Wave wv == head wv (cols wv*32..wv*32+31). Per-wave GEMM: M=32 (i<2),
// N=32 (j<2), K=256 (kt<8).
// A-tile LDS layout: kb-PAIR chunks of 520 elems (1024B data + 16B pad) ->
// ds_read_b128 fragments are 2-way bank-aliased (free). Staged with
// global_load_lds (linear 1KB chunks, 2 per wave).
// Weights streamed from L2 inside the unrolled kt loop (compiler pipelines).
__global__ __launch_bounds__(512) void mega_kernel(
    const __hip_bfloat16* __restrict__ xt,    // [B*V][4096][256]
    const __hip_bfloat16* __restrict__ xbar,  // [B][4096][256]
    const __hip_bfloat16* __restrict__ Wq,
    const __hip_bfloat16* __restrict__ Wk,
    const __hip_bfloat16* __restrict__ Wv,
    const __hip_bfloat16* __restrict__ Wo,
    float* __restrict__ out)                  // [B][256][4096]
{
    __shared__ __align__(16) __hip_bfloat16 Abuf[2][8320];   // 2 x 16.25 KB
    const size_t SL = (size_t)HW * C_DIM;
    const int w0 = blockIdx.x * 32;
    const int b  = blockIdx.y;
    const int t  = threadIdx.x, wv = t >> 6, l = t & 63;
    const int g = l >> 4, rl = l & 15;

    // stage 32x256 bf16 tile: 16 chunks of 1KB (kb-pair each), 2 per wave.
    // lane l of chunk ch covers (kb = ch*2 + (l>>5), row = l&31).
    auto stageA = [&](int buf, const __hip_bfloat16* src) {
#pragma unroll
        for (int c2 = 0; c2 < 2; ++c2) {
            const int ch = wv * 2 + c2;
            const int kb = ch * 2 + (l >> 5);
            const __hip_bfloat16* gp = src + (size_t)(w0 + (l & 31)) * 256 + kb * 8;
            __builtin_amdgcn_global_load_lds(
                (const __attribute__((address_space(1))) void*)gp,
                (__attribute__((address_space(3))) void*)(&Abuf[buf][ch * 520]),
                16, 0, 0);
        }
    };

    // A fragment: rows i*16+rl, k-block kt*4+g.  elem = kbp*520 + (kb&1)*256 + row*8
    auto ldA = [&](int buf, int kt, int i) -> bf16x8 {
        const int kb = kt * 4 + g;
        return *(const bf16x8*)&Abuf[buf][(kb >> 1) * 520 + (kb & 1) * 256 + (i * 16 + rl) * 8];
    };
    // B fragment of W: col wv*32+j*16+rl, k = kt*32+g*8
    auto ldB = [&](const __hip_bfloat16* W, int j, int kt) -> bf16x8 {
        return *(const bf16x8*)(W + (size_t)(wv * 32 + j * 16 + rl) * 256 + kt * 32 + g * 8);
    };

    f32x4 Kacc[2][2], Vacc[2][2], oacc[2][2];

    // single-matrix GEMM into Kacc (used for Q and Wo phases)
    auto gemm1 = [&](int buf, const __hip_bfloat16* W) {
#pragma unroll
        for (int i = 0; i < 2; ++i)
#pragma unroll
            for (int j = 0; j < 2; ++j) {
                Kacc[i][j][0] = 0.f; Kacc[i][j][1] = 0.f;
                Kacc[i][j][2] = 0.f; Kacc[i][j][3] = 0.f;
            }
#pragma unroll
        for (int kt = 0; kt < 8; ++kt) {
            bf16x8 b0 = ldB(W, 0, kt), b1 = ldB(W, 1, kt);
            bf16x8 a0 = ldA(buf, kt, 0), a1 = ldA(buf, kt, 1);
            Kacc[0][0] = __builtin_amdgcn_mfma_f32_16x16x32_bf16(a0, b0, Kacc[0][0], 0, 0, 0);
            Kacc[0][1] = __builtin_amdgcn_mfma_f32_16x16x32_bf16(a0, b1, Kacc[0][1], 0, 0, 0);
            Kacc[1][0] = __builtin_amdgcn_mfma_f32_16x16x32_bf16(a1, b0, Kacc[1][0], 0, 0, 0);
            Kacc[1][1] = __builtin_amdgcn_mfma_f32_16x16x32_bf16(a1, b1, Kacc[1][1], 0, 0, 0);
        }
    };

    // fused K+V GEMM: one pass over the A-tile, both accumulators
    auto gemmKV = [&](int buf) {
#pragma unroll
        for (int i = 0; i < 2; ++i)
#pragma unroll
            for (int j = 0; j < 2; ++j) {
#pragma unroll
                for (int r = 0; r < 4; ++r) { Kacc[i][j][r] = 0.f; Vacc[i][j][r] = 0.f; }
            }
#pragma unroll
        for (int kt = 0; kt < 8; ++kt) {
            bf16x8 bk0 = ldB(Wk, 0, kt), bk1 = ldB(Wk, 1, kt);
            bf16x8 bv0 = ldB(Wv, 0, kt), bv1 = ldB(Wv, 1, kt);
            bf16x8 a0 = ldA(buf, kt, 0), a1 = ldA(buf, kt, 1);
            Kacc[0][0] = __builtin_amdgcn_mfma_f32_16x16x32_bf16(a0, bk0, Kacc[0][0], 0, 0, 0);
            Vacc[0][0] = __builtin_amdgcn_mfma_f32_16x16x32_bf16(a0, bv0, Vacc[0][0], 0, 0, 0);
            Kacc[0][1] = __builtin_amdgcn_mfma_f32_16x16x32_bf16(a0, bk1, Kacc[0][1], 0, 0, 0);
            Vacc[0][1] = __builtin_amdgcn_mfma_f32_16x16x32_bf16(a0, bv1, Vacc[0][1], 0, 0, 0);
            Kacc[1][0] = __builtin_amdgcn_mfma_f32_16x16x32_bf16(a1, bk0, Kacc[1][0], 0, 0, 0);
            Vacc[1][0] = __builtin_amdgcn_mfma_f32_16x16x32_bf16(a1, bv0, Vacc[1][0], 0, 0, 0);
            Kacc[1][1] = __builtin_amdgcn_mfma_f32_16x16x32_bf16(a1, bk1, Kacc[1][1], 0, 0, 0);
            Vacc[1][1] = __builtin_amdgcn_mfma_f32_16x16x32_bf16(a1, bv1, Vacc[1][1], 0, 0, 0);
        }
    };

    // ---- prologue + Q phase ----
    stageA(0, xbar + (size_t)b * SL);
    __syncthreads();                          // S0: xbar tile ready
    gemm1(0, Wq);                             // Q -> Kacc
    stageA(1, xt + (size_t)(b * NV) * SL);    // view-0 tile (drains at S1)

    // pack Q (pre-scaled) as bf16: 8 VGPRs
    const float scale = 0.17677669529663687f; // 32^-0.5
    bf16x4 qb[2][2];
#pragma unroll
    for (int i = 0; i < 2; ++i)
#pragma unroll
        for (int j = 0; j < 2; ++j)
#pragma unroll
            for (int r = 0; r < 4; ++r)
                qb[i][j][r] = (__bf16)(Kacc[i][j][r] * scale);

    float m[2][4], den[2][4];
#pragma unroll
    for (int i = 0; i < 2; ++i)
#pragma unroll
        for (int r = 0; r < 4; ++r) { m[i][r] = -1e30f; den[i][r] = 0.f; }
#pragma unroll
    for (int i = 0; i < 2; ++i)
#pragma unroll
        for (int j = 0; j < 2; ++j) {
            oacc[i][j][0] = 0.f; oacc[i][j][1] = 0.f;
            oacc[i][j][2] = 0.f; oacc[i][j][3] = 0.f;
        }
    __syncthreads();                          // S1: view-0 staged

    // ---- view loop: one A-pass per view, softmax fully in registers ----
    for (int v = 0; v < NV; ++v) {
        const int buf = (v + 1) & 1;          // v0->1, v1->0, ...
        if (v < NV - 1) stageA(buf ^ 1, xt + (size_t)(b * NV + v + 1) * SL);
        gemmKV(buf);

#pragma unroll
        for (int i = 0; i < 2; ++i)
#pragma unroll
            for (int r = 0; r < 4; ++r) {
                // row = i*16 + g*4 + r ; sum Q*K over this head's 32 cols
                float s = (float)qb[i][0][r] * Kacc[i][0][r]
                        + (float)qb[i][1][r] * Kacc[i][1][r];
                s += __shfl_xor(s, 1);
                s += __shfl_xor(s, 2);
                s += __shfl_xor(s, 4);
                s += __shfl_xor(s, 8);        // 16-lane group sum -> full row sum
                const float mn = fmaxf(m[i][r], s);
                const float f  = __expf(m[i][r] - mn);
                const float e  = __expf(s - mn);
                den[i][r] = den[i][r] * f + e;
                m[i][r]   = mn;
#pragma unroll
                for (int j = 0; j < 2; ++j) {
                    oacc[i][j][r] = oacc[i][j][r] * f + e * Vacc[i][j][r];
                }
            }
        __syncthreads();                      // B(v): next tile ready; buf free for v+2
    }

    // ---- epilogue: attn tile (bf16, A-layout) -> Abuf[0], Wo GEMM, stores ----
#pragma unroll
    for (int i = 0; i < 2; ++i)
#pragma unroll
        for (int r = 0; r < 4; ++r) {
            const float inv = 1.f / den[i][r];
            const int row = i * 16 + g * 4 + r;
#pragma unroll
            for (int j = 0; j < 2; ++j) {
                const int c  = wv * 32 + j * 16 + rl;
                const int kb = c >> 3;
                Abuf[0][(kb >> 1) * 520 + (kb & 1) * 256 + row * 8 + (c & 7)] =
                    __float2bfloat16(oacc[i][j][r] * inv);
            }
        }
    __syncthreads();                          // S6: attn tile ready
    gemm1(0, Wo);                             // out tile -> Kacc

    float* op = out + (size_t)b * C_DIM * HW;
#pragma unroll
    for (int i = 0; i < 2; ++i)
#pragma unroll
        for (int j = 0; j < 2; ++j) {
            const int col = wv * 32 + j * 16 + rl;
            *(f32x4*)(op + (size_t)col * HW + w0 + i * 16 + g * 4) = Kacc[i][j];
        }
}

extern "C" void kernel_launch(void* const* d_in, const int* in_sizes, int n_in,
                              void* d_out, int out_size, void* d_ws, size_t ws_size,
                              hipStream_t stream)
{
    const float* x  = (const float*)d_in[0];
    const float* Wq = (const float*)d_in[1];
    const float* Wk = (const float*)d_in[2];
    const float* Wv = (const float*)d_in[3];
    const float* Wo = (const float*)d_in[4];
    (void)in_sizes; (void)n_in; (void)out_size; (void)ws_size;

    char* ws = (char*)d_ws;
    const size_t MB = 1024ull * 1024ull;
    const size_t SL = (size_t)HW * C_DIM;

    __hip_bfloat16* Wbf  = (__hip_bfloat16*)(ws);            // 512 KB
    __hip_bfloat16* xt   = (__hip_bfloat16*)(ws + 1 * MB);   // 48 MB [4*6][4096][256]
    __hip_bfloat16* xbar = (__hip_bfloat16*)(ws + 49 * MB);  // 8 MB  [4][4096][256]

    const __hip_bfloat16* WqB = Wbf;
    const __hip_bfloat16* WkB = Wbf + 65536;
    const __hip_bfloat16* WvB = Wbf + 131072;
    const __hip_bfloat16* WoB = Wbf + 196608;

    convert_weights_kernel<<<dim3(256, 4), 256, 0, stream>>>(Wq, Wk, Wv, Wo, Wbf);
    transpose_mean_kernel<<<dim3(HW / 64, C_DIM / 64, NB), 256, 0, stream>>>(x, xt, xbar);
    mega_kernel<<<dim3(HW / 32, NB), 512, 0, stream>>>(xt, xbar, WqB, WkB, WvB, WoB, (float*)d_out);
}